// Round 10
// baseline (1862.223 us; speedup 1.0000x reference)
//
#include <hip/hip_runtime.h>

#define N_NODES 100000
#define N_EDGES 1600000
#define NB 391  // ceil(N_NODES/256)
#define NTASK (N_NODES / 16)  // 6250
#define COLPAD (N_EDGES + 7 * N_NODES + 64)  // padded CSR + slack

typedef unsigned short ushort_t;
typedef __attribute__((ext_vector_type(8))) short bf16x8;
typedef __attribute__((ext_vector_type(4))) float f32x4;
typedef __attribute__((ext_vector_type(4))) unsigned u32x4;  // clang vec: ok for nontemporal builtins

__device__ __forceinline__ float bf2f(unsigned short u) {
    union { unsigned u; float f; } x; x.u = ((unsigned)u) << 16; return x.f;
}
__device__ __forceinline__ unsigned short f2bf(float f) {
    union { float f; unsigned u; } x; x.f = f;
    unsigned r = x.u + 0x7fffu + ((x.u >> 16) & 1u);
    return (unsigned short)(r >> 16);
}

// ---- init: dummy-fill colp, zero cnt, zero dummy hd rows (1 kernel) ----
__global__ void k_init(unsigned* __restrict__ colp, unsigned* __restrict__ cnt,
                       ushort_t* __restrict__ hdA, ushort_t* __restrict__ hdB) {
    int i = blockIdx.x * 256 + threadIdx.x;
    if (i < COLPAD) colp[i] = (unsigned)N_NODES;
    if (i < N_NODES) cnt[i] = 0u;
    if (i < 128) {
        hdA[(size_t)N_NODES * 128 + i] = 0;
        hdB[(size_t)N_NODES * 128 + i] = 0;
    }
}

__global__ void k_deg(const int* __restrict__ dst, unsigned* __restrict__ cnt) {
    int e = blockIdx.x * 256 + threadIdx.x;
    if (e < N_EDGES) atomicAdd(&cnt[dst[e]], 1u);
}

// per-block sums of PADDED counts + dis/sdeg computation (fused)
__global__ void __launch_bounds__(256) k_bsum(const unsigned* __restrict__ cnt,
                                              unsigned* __restrict__ bsum,
                                              float* __restrict__ dis,
                                              float* __restrict__ sdeg) {
    __shared__ unsigned sh[256];
    int i = blockIdx.x * 256 + threadIdx.x;
    unsigned c = (i < N_NODES) ? cnt[i] : 0u;
    if (i < N_NODES) {
        float d = (float)c + 1.0f;
        float s = sqrtf(d);
        sdeg[i] = s;
        dis[i] = 1.0f / s;
    }
    sh[threadIdx.x] = (i < N_NODES) ? ((c + 7u) & ~7u) : 0u;
    __syncthreads();
    for (int off = 128; off > 0; off >>= 1) {
        if (threadIdx.x < off) sh[threadIdx.x] += sh[threadIdx.x + off];
        __syncthreads();
    }
    if (threadIdx.x == 0) bsum[blockIdx.x] = sh[0];
}

// row_ptr build: inline global prefix (each block reduces bsum[0..bid))
__global__ void __launch_bounds__(256) k_apply(const unsigned* __restrict__ cnt,
                                               const unsigned* __restrict__ bsum,
                                               unsigned* __restrict__ prow,
                                               unsigned* __restrict__ cur) {
    __shared__ unsigned sh[256];
    __shared__ unsigned red[256];
    int i = blockIdx.x * 256 + threadIdx.x;
    int t = threadIdx.x;
    unsigned s = 0;
    for (int j = t; j < NB; j += 256)
        if (j < blockIdx.x) s += bsum[j];
    red[t] = s;
    __syncthreads();
    for (int off = 128; off > 0; off >>= 1) {
        if (t < off) red[t] += red[t + off];
        __syncthreads();
    }
    unsigned pre = red[0];
    unsigned v = (i < N_NODES) ? ((cnt[i] + 7u) & ~7u) : 0u;
    sh[t] = v;
    __syncthreads();
    for (int off = 1; off < 256; off <<= 1) {
        unsigned u = (t >= off) ? sh[t - off] : 0u;
        __syncthreads();
        sh[t] += u;
        __syncthreads();
    }
    if (i < N_NODES) {
        prow[i] = pre + sh[t] - v;
        cur[i] = 0u;  // fill cursor (cur aliases cnt; read-before-write per i)
    }
    if (i == N_NODES - 1) prow[N_NODES] = pre + sh[t];
}

__global__ void k_fill(const int* __restrict__ src, const int* __restrict__ dst,
                       const unsigned* __restrict__ prow, unsigned* __restrict__ cur,
                       unsigned* __restrict__ colp) {
    int e = blockIdx.x * 256 + threadIdx.x;
    if (e < N_EDGES) {
        int d = dst[e];
        unsigned pos = prow[d] + atomicAdd(&cur[d], 1u);
        colp[pos] = (unsigned)src[e];
    }
}

// ------- weight transpose + bf16 hi/lo split (5 x 128x128 f32 -> 10 bf16) ----
__global__ void k_tr(const float* __restrict__ Wd, const float* __restrict__ Wf1,
                     const float* __restrict__ Wg, ushort_t* __restrict__ WT) {
    const float* srcs[5] = {Wd, Wf1, Wg, Wd + 128 * 128, Wf1 + 128 * 128};
    const float* S = srcs[blockIdx.x];
    ushort_t* Dhi = WT + (size_t)(2 * blockIdx.x) * 16384;
    ushort_t* Dlo = Dhi + 16384;
    for (int i = threadIdx.x; i < 128 * 128; i += blockDim.x) {
        int n = i >> 7, k = i & 127;
        float w = S[k * 128 + n];
        unsigned short h = f2bf(w);
        Dhi[n * 128 + k] = h;
        Dlo[n * 128 + k] = f2bf(w - bf2f(h));
    }
}

// ---------------- preproc: x -> h0 -> ni(bf16), hd(bf16) ----------------
__global__ void __launch_bounds__(128) k_pre1(
    const float* __restrict__ x, const float* __restrict__ Wp,
    const float* __restrict__ bp, const float* __restrict__ W1,
    const float* __restrict__ b1, const float* __restrict__ W2,
    const float* __restrict__ b2, const float* __restrict__ dis,
    ushort_t* __restrict__ ni, ushort_t* __restrict__ hd) {
    __shared__ float h0s[4][32];
    int j = threadIdx.x;  // 0..127
    long n0 = (long)blockIdx.x * 4;
    {
        int nn = j >> 5, c = j & 31;
        float acc = bp[c];
#pragma unroll
        for (int k = 0; k < 8; ++k)
            acc += x[(n0 + nn) * 8 + k] * Wp[k * 32 + c];
        h0s[nn][c] = acc;  // preproc activation = none
    }
    __syncthreads();
    float ni_a[4], h1_a[4];
    float bb1 = b1[j], bb2 = b2[j];
#pragma unroll
    for (int m = 0; m < 4; ++m) { ni_a[m] = bb1; h1_a[m] = bb2; }
    for (int cc = 0; cc < 32; ++cc) {
        float w1 = W1[cc * 128 + j];
        float w2 = W2[cc * 128 + j];
#pragma unroll
        for (int m = 0; m < 4; ++m) {
            float h0v = h0s[m][cc];
            ni_a[m] += h0v * w1;
            h1_a[m] += h0v * w2;
        }
    }
#pragma unroll
    for (int m = 0; m < 4; ++m) {
        long node = n0 + m;
        ni[node * 128 + j] = f2bf(fmaxf(ni_a[m], 0.f));
        hd[node * 128 + j] = f2bf(fmaxf(h1_a[m], 0.f) * dis[node]);
    }
}

// helper: load 4 split A-fragments from an f32 row pointer (chunks stride 32)
__device__ __forceinline__ void load_split_frags(const float* __restrict__ p,
                                                 bf16x8* ahi, bf16x8* alo) {
#pragma unroll
    for (int kc = 0; kc < 4; ++kc) {
        const float* q = p + kc * 32;
#pragma unroll
        for (int j = 0; j < 8; ++j) {
            float f = q[j];
            unsigned short h = f2bf(f);
            ahi[kc][j] = (short)h;
            alo[kc][j] = (short)f2bf(f - bf2f(h));
        }
    }
}

__device__ __forceinline__ void mfma_tiles(const bf16x8* ahi, const bf16x8* alo,
                                           const ushort_t* __restrict__ WThi,
                                           const ushort_t* __restrict__ WTlo,
                                           int r16, int q, f32x4* acc) {
#pragma unroll
    for (int t = 0; t < 8; ++t) {
        const ushort_t* bh = WThi + (t * 16 + r16) * 128 + q * 8;
        const ushort_t* bl = WTlo + (t * 16 + r16) * 128 + q * 8;
#pragma unroll
        for (int kc = 0; kc < 4; ++kc) {
            bf16x8 bhv = *(const bf16x8*)(bh + kc * 32);
            bf16x8 blv = *(const bf16x8*)(bl + kc * 32);
            acc[t] = __builtin_amdgcn_mfma_f32_16x16x32_bf16(alo[kc], bhv, acc[t], 0, 0, 0);
            acc[t] = __builtin_amdgcn_mfma_f32_16x16x32_bf16(ahi[kc], blv, acc[t], 0, 0, 0);
            acc[t] = __builtin_amdgcn_mfma_f32_16x16x32_bf16(ahi[kc], bhv, acc[t], 0, 0, 0);
        }
    }
}

// ------- k_niw: ni(bf16) @ {Wd_top, Wf1_top} + {bd, bf1} -> niWd, niWf -------
__global__ void __launch_bounds__(256) k_niw(
    const ushort_t* __restrict__ in,
    const ushort_t* __restrict__ hiA, const ushort_t* __restrict__ loA,
    const float* __restrict__ biasA, ushort_t* __restrict__ outA,
    const ushort_t* __restrict__ hiB, const ushort_t* __restrict__ loB,
    const float* __restrict__ biasB, ushort_t* __restrict__ outB) {
    int task = blockIdx.x * 4 + (threadIdx.x >> 6);
    if (task >= NTASK) return;
    int lane = threadIdx.x & 63;
    int q = lane >> 4, r16 = lane & 15;
    long base = (long)task * 16;

    bf16x8 a[4];
    const ushort_t* arow = in + (base + r16) * 128 + q * 8;
#pragma unroll
    for (int kc = 0; kc < 4; ++kc) a[kc] = *(const bf16x8*)(arow + kc * 32);

    f32x4 accA[8], accB[8];
#pragma unroll
    for (int t = 0; t < 8; ++t) { accA[t] = {0.f, 0.f, 0.f, 0.f}; accB[t] = {0.f, 0.f, 0.f, 0.f}; }
#pragma unroll
    for (int t = 0; t < 8; ++t) {
        const ushort_t* bhA = hiA + (t * 16 + r16) * 128 + q * 8;
        const ushort_t* blA = loA + (t * 16 + r16) * 128 + q * 8;
        const ushort_t* bhB = hiB + (t * 16 + r16) * 128 + q * 8;
        const ushort_t* blB = loB + (t * 16 + r16) * 128 + q * 8;
#pragma unroll
        for (int kc = 0; kc < 4; ++kc) {
            accA[t] = __builtin_amdgcn_mfma_f32_16x16x32_bf16(a[kc], *(const bf16x8*)(blA + kc * 32), accA[t], 0, 0, 0);
            accA[t] = __builtin_amdgcn_mfma_f32_16x16x32_bf16(a[kc], *(const bf16x8*)(bhA + kc * 32), accA[t], 0, 0, 0);
            accB[t] = __builtin_amdgcn_mfma_f32_16x16x32_bf16(a[kc], *(const bf16x8*)(blB + kc * 32), accB[t], 0, 0, 0);
            accB[t] = __builtin_amdgcn_mfma_f32_16x16x32_bf16(a[kc], *(const bf16x8*)(bhB + kc * 32), accB[t], 0, 0, 0);
        }
    }
#pragma unroll
    for (int t = 0; t < 8; ++t) {
        int n = t * 16 + r16;
        float bvA = biasA[n], bvB = biasB[n];
#pragma unroll
        for (int r = 0; r < 4; ++r) {
            long node = base + q * 4 + r;
            __builtin_nontemporal_store(f2bf(accA[t][r] + bvA), &outA[node * 128 + n]);
            __builtin_nontemporal_store(f2bf(accB[t][r] + bvB), &outB[node * 128 + n]);
        }
    }
}

// accumulate 8 bf16 features (one uint4) into a[0..7]
__device__ __forceinline__ void acc8(uint4 w, float* a) {
    a[0] += __uint_as_float(w.x << 16);
    a[1] += __uint_as_float(w.x & 0xffff0000u);
    a[2] += __uint_as_float(w.y << 16);
    a[3] += __uint_as_float(w.y & 0xffff0000u);
    a[4] += __uint_as_float(w.z << 16);
    a[5] += __uint_as_float(w.z & 0xffff0000u);
    a[6] += __uint_as_float(w.w << 16);
    a[7] += __uint_as_float(w.w & 0xffff0000u);
}

__device__ __forceinline__ void gather8(uint4* G, u32x4 c0, u32x4 c1,
                                        const uint4* __restrict__ h4, int l) {
    G[0] = h4[(long)c0.x * 16 + l];
    G[1] = h4[(long)c0.y * 16 + l];
    G[2] = h4[(long)c0.z * 16 + l];
    G[3] = h4[(long)c0.w * 16 + l];
    G[4] = h4[(long)c1.x * 16 + l];
    G[5] = h4[(long)c1.y * 16 + l];
    G[6] = h4[(long)c1.z * 16 + l];
    G[7] = h4[(long)c1.w * 16 + l];
}

__device__ __forceinline__ void accbatch(const uint4* G, float* a) {
#pragma unroll
    for (int j = 0; j < 8; ++j) acc8(G[j], a);
}

// ---- fused layer: pipelined gather (padded CSR) -> LDS -> GEMM1 -> GEMM2 ----
// hd_out = relu(niWd + relu((z@Wg)*dis + bg) @ Wd_bot) * dis   (bf16)
// Streaming data (colp, niWd, hd_out) is non-temporal: leave L2 to the
// gather-row working set (avg 2.3 touches/row per XCD).
__global__ void __launch_bounds__(256, 4) k_fused(
    const unsigned* __restrict__ prow, const unsigned* __restrict__ colp,
    const ushort_t* __restrict__ hd_in,
    const ushort_t* __restrict__ hi_wg, const ushort_t* __restrict__ lo_wg,
    const float* __restrict__ bg,
    const ushort_t* __restrict__ hi_wd, const ushort_t* __restrict__ lo_wd,
    const ushort_t* __restrict__ niWd, const float* __restrict__ dis,
    ushort_t* __restrict__ hd_out) {
    __shared__ float gsh[4][16 * 132];  // per-wave 8448 B slab
    int wid = threadIdx.x >> 6;
    int lane = threadIdx.x & 63;
    int task = blockIdx.x * 4 + wid;
    if (task >= NTASK) return;
    long base = (long)task * 16;
    float* gw = gsh[wid];
    const uint4* h4 = (const uint4*)hd_in;  // 16 uint4 per 128-feature row

    int g = lane >> 4;   // group 0..3
    int l = lane & 15;   // lane in group; covers features 8l..8l+7

    // ---- gather phase: group g aggregates nodes base+4g .. base+4g+3 ----
#pragma unroll 1
    for (int i = 0; i < 4; ++i) {
        int m = g * 4 + i;
        long node = base + m;
        float a[8] = {0.f, 0.f, 0.f, 0.f, 0.f, 0.f, 0.f, 0.f};
        uint4 own = h4[node * 16 + l];
        unsigned t0 = prow[node];
        int nb = (int)((prow[node + 1] - t0) >> 3);  // uniform batches of 8
        acc8(own, a);
        if (nb > 0) {
            const u32x4* cp = (const u32x4*)(colp + t0);  // t0 mult of 8 -> aligned
            u32x4 cX0 = __builtin_nontemporal_load(cp);
            u32x4 cX1 = __builtin_nontemporal_load(cp + 1);
            u32x4 cY0 = __builtin_nontemporal_load(cp + 2);
            u32x4 cY1 = __builtin_nontemporal_load(cp + 3);
            cp += 4;
            uint4 GA[8], GB[8];
            gather8(GA, cX0, cX1, h4, l);
            int k = 0;
            for (; k + 2 < nb; k += 2) {
                cX0 = __builtin_nontemporal_load(cp);
                cX1 = __builtin_nontemporal_load(cp + 1);
                gather8(GB, cY0, cY1, h4, l);    // batch k+1 (GA stays in flight)
                accbatch(GA, a);                 // batch k
                cY0 = __builtin_nontemporal_load(cp + 2);
                cY1 = __builtin_nontemporal_load(cp + 3);
                cp += 4;
                gather8(GA, cX0, cX1, h4, l);    // batch k+2
                accbatch(GB, a);                 // batch k+1
            }
            if (nb - k == 2) {
                gather8(GB, cY0, cY1, h4, l);
                accbatch(GA, a);
                accbatch(GB, a);
            } else {
                accbatch(GA, a);
            }
        }
        float* dstp = gw + m * 132 + 8 * l;
        *(float4*)dstp = make_float4(a[0], a[1], a[2], a[3]);
        *(float4*)(dstp + 4) = make_float4(a[4], a[5], a[6], a[7]);
    }

    // ---- GEMM1: g = relu((z@Wg)*dis + bg) ----
    int q = lane >> 4, r16 = lane & 15;
    bf16x8 ahi[4], alo[4];
    load_split_frags(gw + r16 * 132 + q * 8, ahi, alo);

    f32x4 acc[8];
#pragma unroll
    for (int t = 0; t < 8; ++t) acc[t] = {0.f, 0.f, 0.f, 0.f};
    mfma_tiles(ahi, alo, hi_wg, lo_wg, r16, q, acc);

    float sc[4];
#pragma unroll
    for (int r = 0; r < 4; ++r) sc[r] = dis[base + q * 4 + r];

#pragma unroll
    for (int t = 0; t < 8; ++t) {
        int n = t * 16 + r16;
        float bv = bg[n];
#pragma unroll
        for (int r = 0; r < 4; ++r) {
            int m = q * 4 + r;
            gw[m * 132 + n] = fmaxf(acc[t][r] * sc[r] + bv, 0.f);
        }
    }

    // ---- GEMM2: hd_out = relu(acc + niWd) * dis ----
    load_split_frags(gw + r16 * 132 + q * 8, ahi, alo);
#pragma unroll
    for (int t = 0; t < 8; ++t) acc[t] = {0.f, 0.f, 0.f, 0.f};
    mfma_tiles(ahi, alo, hi_wd, lo_wd, r16, q, acc);

#pragma unroll
    for (int t = 0; t < 8; ++t) {
        int n = t * 16 + r16;
#pragma unroll
        for (int r = 0; r < 4; ++r) {
            long node = base + q * 4 + r;
            float nv = bf2f(__builtin_nontemporal_load(&niWd[node * 128 + n]));
            __builtin_nontemporal_store(f2bf(fmaxf(acc[t][r] + nv, 0.f) * sc[r]),
                                        &hd_out[node * 128 + n]);
        }
    }
}

// ---- k_final: fc1 + fc2 fused ----
// hf = relu((hd@Wf1_bot)*sdeg + niWf); out = hf @ Wf2 + bf2   ([N,2] f32)
__global__ void __launch_bounds__(256) k_final(
    const ushort_t* __restrict__ in, const ushort_t* __restrict__ WThi,
    const ushort_t* __restrict__ WTlo, const ushort_t* __restrict__ niWf,
    const float* __restrict__ sdeg, const float* __restrict__ Wf2,
    const float* __restrict__ bf2v, float* __restrict__ out) {
    int task = blockIdx.x * 4 + (threadIdx.x >> 6);
    if (task >= NTASK) return;
    int lane = threadIdx.x & 63;
    int q = lane >> 4, r16 = lane & 15;
    long base = (long)task * 16;

    bf16x8 a[4];
    const ushort_t* arow = in + (base + r16) * 128 + q * 8;
#pragma unroll
    for (int kc = 0; kc < 4; ++kc) a[kc] = *(const bf16x8*)(arow + kc * 32);

    f32x4 acc[8];
#pragma unroll
    for (int t = 0; t < 8; ++t) acc[t] = {0.f, 0.f, 0.f, 0.f};
#pragma unroll
    for (int t = 0; t < 8; ++t) {
        const ushort_t* bh = WThi + (t * 16 + r16) * 128 + q * 8;
        const ushort_t* bl = WTlo + (t * 16 + r16) * 128 + q * 8;
#pragma unroll
        for (int kc = 0; kc < 4; ++kc) {
            bf16x8 bhv = *(const bf16x8*)(bh + kc * 32);
            bf16x8 blv = *(const bf16x8*)(bl + kc * 32);
            acc[t] = __builtin_amdgcn_mfma_f32_16x16x32_bf16(a[kc], blv, acc[t], 0, 0, 0);
            acc[t] = __builtin_amdgcn_mfma_f32_16x16x32_bf16(a[kc], bhv, acc[t], 0, 0, 0);
        }
    }

    float sc[4];
#pragma unroll
    for (int r = 0; r < 4; ++r) sc[r] = sdeg[base + q * 4 + r];

    float p0[4] = {0.f, 0.f, 0.f, 0.f}, p1[4] = {0.f, 0.f, 0.f, 0.f};
#pragma unroll
    for (int t = 0; t < 8; ++t) {
        int n = t * 16 + r16;
        float2 w2 = ((const float2*)Wf2)[n];
#pragma unroll
        for (int r = 0; r < 4; ++r) {
            long node = base + q * 4 + r;
            float v = fmaxf(acc[t][r] * sc[r] + bf2f(niWf[node * 128 + n]), 0.f);
            p0[r] += v * w2.x;
            p1[r] += v * w2.y;
        }
    }
#pragma unroll
    for (int step = 1; step < 16; step <<= 1) {
#pragma unroll
        for (int r = 0; r < 4; ++r) {
            p0[r] += __shfl_xor(p0[r], step, 64);
            p1[r] += __shfl_xor(p1[r], step, 64);
        }
    }
    if (r16 == 0) {
        float b0 = bf2v[0], b1v = bf2v[1];
#pragma unroll
        for (int r = 0; r < 4; ++r) {
            long node = base + q * 4 + r;
            float2 o; o.x = p0[r] + b0; o.y = p1[r] + b1v;
            ((float2*)out)[node] = o;
        }
    }
}

extern "C" void kernel_launch(void* const* d_in, const int* in_sizes, int n_in,
                              void* d_out, int out_size, void* d_ws, size_t ws_size,
                              hipStream_t stream) {
    const float* x    = (const float*)d_in[0];
    const int* ei     = (const int*)d_in[1];
    const float* Wp   = (const float*)d_in[2];
    const float* bp   = (const float*)d_in[3];
    const float* W1   = (const float*)d_in[4];
    const float* b1   = (const float*)d_in[5];
    const float* W2   = (const float*)d_in[6];
    const float* b2   = (const float*)d_in[7];
    const float* Wg   = (const float*)d_in[8];
    const float* bg   = (const float*)d_in[9];
    const float* Wd   = (const float*)d_in[10];
    const float* bd   = (const float*)d_in[11];
    const float* Wf1  = (const float*)d_in[12];
    const float* bf1  = (const float*)d_in[13];
    const float* Wf2  = (const float*)d_in[14];
    const float* bf2v = (const float*)d_in[15];

    // workspace carve (256B aligned)
    char* w = (char*)d_ws;
    auto carve = [&](size_t bytes) {
        void* p = (void*)w;
        w += (bytes + 255) & ~(size_t)255;
        return p;
    };
    float* dis      = (float*)carve((size_t)N_NODES * 4);
    float* sdeg     = (float*)carve((size_t)N_NODES * 4);
    unsigned* cnt   = (unsigned*)carve((size_t)N_NODES * 4);
    unsigned* bsum  = (unsigned*)carve((size_t)NB * 4);
    unsigned* prow  = (unsigned*)carve((size_t)(N_NODES + 1) * 4);
    unsigned* colp  = (unsigned*)carve((size_t)COLPAD * 4);
    ushort_t* hdA   = (ushort_t*)carve((size_t)(N_NODES + 1) * 128 * 2);
    ushort_t* hdB   = (ushort_t*)carve((size_t)(N_NODES + 1) * 128 * 2);
    ushort_t* niB   = (ushort_t*)carve((size_t)N_NODES * 128 * 2);
    ushort_t* niWd  = (ushort_t*)carve((size_t)N_NODES * 128 * 2);
    ushort_t* niWf  = (ushort_t*)carve((size_t)N_NODES * 128 * 2);
    ushort_t* WT    = (ushort_t*)carve((size_t)10 * 16384 * 2);
    ushort_t* hi_wdtop  = WT + 0 * 16384; ushort_t* lo_wdtop  = WT + 1 * 16384;
    ushort_t* hi_wf1top = WT + 2 * 16384; ushort_t* lo_wf1top = WT + 3 * 16384;
    ushort_t* hi_wg     = WT + 4 * 16384; ushort_t* lo_wg     = WT + 5 * 16384;
    ushort_t* hi_wdbot  = WT + 6 * 16384; ushort_t* lo_wdbot  = WT + 7 * 16384;
    ushort_t* hi_wf1bot = WT + 8 * 16384; ushort_t* lo_wf1bot = WT + 9 * 16384;

    const int* srcp = ei;
    const int* dstp = ei + N_EDGES;

    const int GE = (N_EDGES + 255) / 256;    // 6250
    const int GP = (COLPAD + 255) / 256;
    const int GG = (NTASK + 3) / 4;          // 1563

    k_init<<<GP, 256, 0, stream>>>(colp, cnt, hdA, hdB);
    k_deg<<<GE, 256, 0, stream>>>(dstp, cnt);
    k_bsum<<<NB, 256, 0, stream>>>(cnt, bsum, dis, sdeg);
    k_apply<<<NB, 256, 0, stream>>>(cnt, bsum, prow, cnt);
    k_fill<<<GE, 256, 0, stream>>>(srcp, dstp, prow, cnt, colp);
    k_tr<<<5, 256, 0, stream>>>(Wd, Wf1, Wg, WT);
    k_pre1<<<N_NODES / 4, 128, 0, stream>>>(x, Wp, bp, W1, b1, W2, b2, dis, niB, hdA);
    k_niw<<<GG, 256, 0, stream>>>(niB, hi_wdtop, lo_wdtop, bd, niWd,
                                  hi_wf1top, lo_wf1top, bf1, niWf);
    ushort_t* hin = hdA;
    ushort_t* hout = hdB;
    for (int l = 0; l < 8; ++l) {
        k_fused<<<GG, 256, 0, stream>>>(prow, colp, hin, hi_wg, lo_wg, bg,
                                        hi_wdbot, lo_wdbot, niWd, dis, hout);
        ushort_t* tmp = hin; hin = hout; hout = tmp;
    }
    k_final<<<GG, 256, 0, stream>>>(hin, hi_wf1bot, lo_wf1bot, niWf, sdeg,
                                    Wf2, bf2v, (float*)d_out);
}

// Round 11
// 1757.124 us; speedup vs baseline: 1.0598x; 1.0598x over previous
//
#include <hip/hip_runtime.h>

#define N_NODES 100000
#define N_EDGES 1600000
#define NB 391  // ceil(N_NODES/256)
#define NTASK (N_NODES / 16)  // 6250
#define COLPAD (N_EDGES + 7 * N_NODES + 64)  // padded CSR + slack

typedef unsigned short ushort_t;
typedef __attribute__((ext_vector_type(8))) short bf16x8;
typedef __attribute__((ext_vector_type(4))) float f32x4;

__device__ __forceinline__ float bf2f(unsigned short u) {
    union { unsigned u; float f; } x; x.u = ((unsigned)u) << 16; return x.f;
}
__device__ __forceinline__ unsigned short f2bf(float f) {
    union { float f; unsigned u; } x; x.f = f;
    unsigned r = x.u + 0x7fffu + ((x.u >> 16) & 1u);
    return (unsigned short)(r >> 16);
}

// ---- init: dummy-fill colp, zero cnt, zero dummy hd rows (1 kernel) ----
__global__ void k_init(unsigned* __restrict__ colp, unsigned* __restrict__ cnt,
                       ushort_t* __restrict__ hdA, ushort_t* __restrict__ hdB) {
    int i = blockIdx.x * 256 + threadIdx.x;
    if (i < COLPAD) colp[i] = (unsigned)N_NODES;
    if (i < N_NODES) cnt[i] = 0u;
    if (i < 128) {
        hdA[(size_t)N_NODES * 128 + i] = 0;
        hdB[(size_t)N_NODES * 128 + i] = 0;
    }
}

__global__ void k_deg(const int* __restrict__ dst, unsigned* __restrict__ cnt) {
    int e = blockIdx.x * 256 + threadIdx.x;
    if (e < N_EDGES) atomicAdd(&cnt[dst[e]], 1u);
}

// per-block sums of PADDED counts + dis/sdeg computation (fused)
__global__ void __launch_bounds__(256) k_bsum(const unsigned* __restrict__ cnt,
                                              unsigned* __restrict__ bsum,
                                              float* __restrict__ dis,
                                              float* __restrict__ sdeg) {
    __shared__ unsigned sh[256];
    int i = blockIdx.x * 256 + threadIdx.x;
    unsigned c = (i < N_NODES) ? cnt[i] : 0u;
    if (i < N_NODES) {
        float d = (float)c + 1.0f;
        float s = sqrtf(d);
        sdeg[i] = s;
        dis[i] = 1.0f / s;
    }
    sh[threadIdx.x] = (i < N_NODES) ? ((c + 7u) & ~7u) : 0u;
    __syncthreads();
    for (int off = 128; off > 0; off >>= 1) {
        if (threadIdx.x < off) sh[threadIdx.x] += sh[threadIdx.x + off];
        __syncthreads();
    }
    if (threadIdx.x == 0) bsum[blockIdx.x] = sh[0];
}

// row_ptr build: inline global prefix (each block reduces bsum[0..bid))
__global__ void __launch_bounds__(256) k_apply(const unsigned* __restrict__ cnt,
                                               const unsigned* __restrict__ bsum,
                                               unsigned* __restrict__ prow,
                                               unsigned* __restrict__ cur) {
    __shared__ unsigned sh[256];
    __shared__ unsigned red[256];
    int i = blockIdx.x * 256 + threadIdx.x;
    int t = threadIdx.x;
    unsigned s = 0;
    for (int j = t; j < NB; j += 256)
        if (j < blockIdx.x) s += bsum[j];
    red[t] = s;
    __syncthreads();
    for (int off = 128; off > 0; off >>= 1) {
        if (t < off) red[t] += red[t + off];
        __syncthreads();
    }
    unsigned pre = red[0];
    unsigned v = (i < N_NODES) ? ((cnt[i] + 7u) & ~7u) : 0u;
    sh[t] = v;
    __syncthreads();
    for (int off = 1; off < 256; off <<= 1) {
        unsigned u = (t >= off) ? sh[t - off] : 0u;
        __syncthreads();
        sh[t] += u;
        __syncthreads();
    }
    if (i < N_NODES) {
        prow[i] = pre + sh[t] - v;
        cur[i] = 0u;  // fill cursor (cur aliases cnt; read-before-write per i)
    }
    if (i == N_NODES - 1) prow[N_NODES] = pre + sh[t];
}

__global__ void k_fill(const int* __restrict__ src, const int* __restrict__ dst,
                       const unsigned* __restrict__ prow, unsigned* __restrict__ cur,
                       unsigned* __restrict__ colp) {
    int e = blockIdx.x * 256 + threadIdx.x;
    if (e < N_EDGES) {
        int d = dst[e];
        unsigned pos = prow[d] + atomicAdd(&cur[d], 1u);
        colp[pos] = (unsigned)src[e];
    }
}

// ------- weight transpose + bf16 hi/lo split (5 x 128x128 f32 -> 10 bf16) ----
__global__ void k_tr(const float* __restrict__ Wd, const float* __restrict__ Wf1,
                     const float* __restrict__ Wg, ushort_t* __restrict__ WT) {
    const float* srcs[5] = {Wd, Wf1, Wg, Wd + 128 * 128, Wf1 + 128 * 128};
    const float* S = srcs[blockIdx.x];
    ushort_t* Dhi = WT + (size_t)(2 * blockIdx.x) * 16384;
    ushort_t* Dlo = Dhi + 16384;
    for (int i = threadIdx.x; i < 128 * 128; i += blockDim.x) {
        int n = i >> 7, k = i & 127;
        float w = S[k * 128 + n];
        unsigned short h = f2bf(w);
        Dhi[n * 128 + k] = h;
        Dlo[n * 128 + k] = f2bf(w - bf2f(h));
    }
}

// ---------------- preproc: x -> h0 -> ni(bf16), hd(bf16) ----------------
__global__ void __launch_bounds__(128) k_pre1(
    const float* __restrict__ x, const float* __restrict__ Wp,
    const float* __restrict__ bp, const float* __restrict__ W1,
    const float* __restrict__ b1, const float* __restrict__ W2,
    const float* __restrict__ b2, const float* __restrict__ dis,
    ushort_t* __restrict__ ni, ushort_t* __restrict__ hd) {
    __shared__ float h0s[4][32];
    int j = threadIdx.x;  // 0..127
    long n0 = (long)blockIdx.x * 4;
    {
        int nn = j >> 5, c = j & 31;
        float acc = bp[c];
#pragma unroll
        for (int k = 0; k < 8; ++k)
            acc += x[(n0 + nn) * 8 + k] * Wp[k * 32 + c];
        h0s[nn][c] = acc;  // preproc activation = none
    }
    __syncthreads();
    float ni_a[4], h1_a[4];
    float bb1 = b1[j], bb2 = b2[j];
#pragma unroll
    for (int m = 0; m < 4; ++m) { ni_a[m] = bb1; h1_a[m] = bb2; }
    for (int cc = 0; cc < 32; ++cc) {
        float w1 = W1[cc * 128 + j];
        float w2 = W2[cc * 128 + j];
#pragma unroll
        for (int m = 0; m < 4; ++m) {
            float h0v = h0s[m][cc];
            ni_a[m] += h0v * w1;
            h1_a[m] += h0v * w2;
        }
    }
#pragma unroll
    for (int m = 0; m < 4; ++m) {
        long node = n0 + m;
        ni[node * 128 + j] = f2bf(fmaxf(ni_a[m], 0.f));
        hd[node * 128 + j] = f2bf(fmaxf(h1_a[m], 0.f) * dis[node]);
    }
}

// helper: load 4 split A-fragments from an f32 row pointer (chunks stride 32)
__device__ __forceinline__ void load_split_frags(const float* __restrict__ p,
                                                 bf16x8* ahi, bf16x8* alo) {
#pragma unroll
    for (int kc = 0; kc < 4; ++kc) {
        const float* q = p + kc * 32;
#pragma unroll
        for (int j = 0; j < 8; ++j) {
            float f = q[j];
            unsigned short h = f2bf(f);
            ahi[kc][j] = (short)h;
            alo[kc][j] = (short)f2bf(f - bf2f(h));
        }
    }
}

__device__ __forceinline__ void mfma_tiles(const bf16x8* ahi, const bf16x8* alo,
                                           const ushort_t* __restrict__ WThi,
                                           const ushort_t* __restrict__ WTlo,
                                           int r16, int q, f32x4* acc) {
#pragma unroll
    for (int t = 0; t < 8; ++t) {
        const ushort_t* bh = WThi + (t * 16 + r16) * 128 + q * 8;
        const ushort_t* bl = WTlo + (t * 16 + r16) * 128 + q * 8;
#pragma unroll
        for (int kc = 0; kc < 4; ++kc) {
            bf16x8 bhv = *(const bf16x8*)(bh + kc * 32);
            bf16x8 blv = *(const bf16x8*)(bl + kc * 32);
            acc[t] = __builtin_amdgcn_mfma_f32_16x16x32_bf16(alo[kc], bhv, acc[t], 0, 0, 0);
            acc[t] = __builtin_amdgcn_mfma_f32_16x16x32_bf16(ahi[kc], blv, acc[t], 0, 0, 0);
            acc[t] = __builtin_amdgcn_mfma_f32_16x16x32_bf16(ahi[kc], bhv, acc[t], 0, 0, 0);
        }
    }
}

// ------- k_niw: ni(bf16) @ {Wd_top, Wf1_top} + {bd, bf1} -> niWd, niWf -------
__global__ void __launch_bounds__(256) k_niw(
    const ushort_t* __restrict__ in,
    const ushort_t* __restrict__ hiA, const ushort_t* __restrict__ loA,
    const float* __restrict__ biasA, ushort_t* __restrict__ outA,
    const ushort_t* __restrict__ hiB, const ushort_t* __restrict__ loB,
    const float* __restrict__ biasB, ushort_t* __restrict__ outB) {
    int task = blockIdx.x * 4 + (threadIdx.x >> 6);
    if (task >= NTASK) return;
    int lane = threadIdx.x & 63;
    int q = lane >> 4, r16 = lane & 15;
    long base = (long)task * 16;

    bf16x8 a[4];
    const ushort_t* arow = in + (base + r16) * 128 + q * 8;
#pragma unroll
    for (int kc = 0; kc < 4; ++kc) a[kc] = *(const bf16x8*)(arow + kc * 32);

    f32x4 accA[8], accB[8];
#pragma unroll
    for (int t = 0; t < 8; ++t) { accA[t] = {0.f, 0.f, 0.f, 0.f}; accB[t] = {0.f, 0.f, 0.f, 0.f}; }
#pragma unroll
    for (int t = 0; t < 8; ++t) {
        const ushort_t* bhA = hiA + (t * 16 + r16) * 128 + q * 8;
        const ushort_t* blA = loA + (t * 16 + r16) * 128 + q * 8;
        const ushort_t* bhB = hiB + (t * 16 + r16) * 128 + q * 8;
        const ushort_t* blB = loB + (t * 16 + r16) * 128 + q * 8;
#pragma unroll
        for (int kc = 0; kc < 4; ++kc) {
            accA[t] = __builtin_amdgcn_mfma_f32_16x16x32_bf16(a[kc], *(const bf16x8*)(blA + kc * 32), accA[t], 0, 0, 0);
            accA[t] = __builtin_amdgcn_mfma_f32_16x16x32_bf16(a[kc], *(const bf16x8*)(bhA + kc * 32), accA[t], 0, 0, 0);
            accB[t] = __builtin_amdgcn_mfma_f32_16x16x32_bf16(a[kc], *(const bf16x8*)(blB + kc * 32), accB[t], 0, 0, 0);
            accB[t] = __builtin_amdgcn_mfma_f32_16x16x32_bf16(a[kc], *(const bf16x8*)(bhB + kc * 32), accB[t], 0, 0, 0);
        }
    }
#pragma unroll
    for (int t = 0; t < 8; ++t) {
        int n = t * 16 + r16;
        float bvA = biasA[n], bvB = biasB[n];
#pragma unroll
        for (int r = 0; r < 4; ++r) {
            long node = base + q * 4 + r;
            outA[node * 128 + n] = f2bf(accA[t][r] + bvA);
            outB[node * 128 + n] = f2bf(accB[t][r] + bvB);
        }
    }
}

// accumulate 8 bf16 features (one uint4) into a[0..7]
__device__ __forceinline__ void acc8(uint4 w, float* a) {
    a[0] += __uint_as_float(w.x << 16);
    a[1] += __uint_as_float(w.x & 0xffff0000u);
    a[2] += __uint_as_float(w.y << 16);
    a[3] += __uint_as_float(w.y & 0xffff0000u);
    a[4] += __uint_as_float(w.z << 16);
    a[5] += __uint_as_float(w.z & 0xffff0000u);
    a[6] += __uint_as_float(w.w << 16);
    a[7] += __uint_as_float(w.w & 0xffff0000u);
}

__device__ __forceinline__ void gather8(uint4* G, uint4 c0, uint4 c1,
                                        const uint4* __restrict__ h4, int l) {
    G[0] = h4[(long)c0.x * 16 + l];
    G[1] = h4[(long)c0.y * 16 + l];
    G[2] = h4[(long)c0.z * 16 + l];
    G[3] = h4[(long)c0.w * 16 + l];
    G[4] = h4[(long)c1.x * 16 + l];
    G[5] = h4[(long)c1.y * 16 + l];
    G[6] = h4[(long)c1.z * 16 + l];
    G[7] = h4[(long)c1.w * 16 + l];
}

__device__ __forceinline__ void accbatch(const uint4* G, float* a) {
#pragma unroll
    for (int j = 0; j < 8; ++j) acc8(G[j], a);
}

// ---- fused layer: pipelined gather (padded CSR) -> LDS -> GEMM1 -> GEMM2 ----
// hd_out = relu(niWd + relu((z@Wg)*dis + bg) @ Wd_bot) * dis   (bf16)
// Gather pipeline: issue order cols(k+2) -> gather(k+1) -> acc(k); in-order
// vmcnt retirement keeps ~16 gather loads + 2 col batches in flight.
// NOTE: non-temporal load/store experiments (R10) REGRESSED: NT stores bypass
// L2 write-back (WRITE_SIZE 37->63 MB) and re-fetch from HBM. Keep regular ops.
__global__ void __launch_bounds__(256, 4) k_fused(
    const unsigned* __restrict__ prow, const unsigned* __restrict__ colp,
    const ushort_t* __restrict__ hd_in,
    const ushort_t* __restrict__ hi_wg, const ushort_t* __restrict__ lo_wg,
    const float* __restrict__ bg,
    const ushort_t* __restrict__ hi_wd, const ushort_t* __restrict__ lo_wd,
    const ushort_t* __restrict__ niWd, const float* __restrict__ dis,
    ushort_t* __restrict__ hd_out) {
    __shared__ float gsh[4][16 * 132];  // per-wave 8448 B slab
    int wid = threadIdx.x >> 6;
    int lane = threadIdx.x & 63;
    int task = blockIdx.x * 4 + wid;
    if (task >= NTASK) return;
    long base = (long)task * 16;
    float* gw = gsh[wid];
    const uint4* h4 = (const uint4*)hd_in;  // 16 uint4 per 128-feature row

    int g = lane >> 4;   // group 0..3
    int l = lane & 15;   // lane in group; covers features 8l..8l+7

    // ---- gather phase: group g aggregates nodes base+4g .. base+4g+3 ----
#pragma unroll 1
    for (int i = 0; i < 4; ++i) {
        int m = g * 4 + i;
        long node = base + m;
        float a[8] = {0.f, 0.f, 0.f, 0.f, 0.f, 0.f, 0.f, 0.f};
        uint4 own = h4[node * 16 + l];
        unsigned t0 = prow[node];
        int nb = (int)((prow[node + 1] - t0) >> 3);  // uniform batches of 8
        acc8(own, a);
        if (nb > 0) {
            const uint4* cp = (const uint4*)(colp + t0);  // t0 mult of 8 -> aligned
            uint4 cX0 = cp[0], cX1 = cp[1];   // batch 0 cols
            uint4 cY0 = cp[2], cY1 = cp[3];   // batch 1 cols (slack-safe)
            cp += 4;
            uint4 GA[8], GB[8];
            gather8(GA, cX0, cX1, h4, l);
            int k = 0;
            for (; k + 2 < nb; k += 2) {
                cX0 = cp[0]; cX1 = cp[1];        // cols(k+2)
                gather8(GB, cY0, cY1, h4, l);    // batch k+1 (GA stays in flight)
                accbatch(GA, a);                 // batch k
                cY0 = cp[2]; cY1 = cp[3];        // cols(k+3) (slack-safe)
                cp += 4;
                gather8(GA, cX0, cX1, h4, l);    // batch k+2
                accbatch(GB, a);                 // batch k+1
            }
            if (nb - k == 2) {
                gather8(GB, cY0, cY1, h4, l);
                accbatch(GA, a);
                accbatch(GB, a);
            } else {
                accbatch(GA, a);
            }
        }
        float* dstp = gw + m * 132 + 8 * l;
        *(float4*)dstp = make_float4(a[0], a[1], a[2], a[3]);
        *(float4*)(dstp + 4) = make_float4(a[4], a[5], a[6], a[7]);
    }

    // ---- GEMM1: g = relu((z@Wg)*dis + bg) ----
    int q = lane >> 4, r16 = lane & 15;
    bf16x8 ahi[4], alo[4];
    load_split_frags(gw + r16 * 132 + q * 8, ahi, alo);

    f32x4 acc[8];
#pragma unroll
    for (int t = 0; t < 8; ++t) acc[t] = {0.f, 0.f, 0.f, 0.f};
    mfma_tiles(ahi, alo, hi_wg, lo_wg, r16, q, acc);

    float sc[4];
#pragma unroll
    for (int r = 0; r < 4; ++r) sc[r] = dis[base + q * 4 + r];

#pragma unroll
    for (int t = 0; t < 8; ++t) {
        int n = t * 16 + r16;
        float bv = bg[n];
#pragma unroll
        for (int r = 0; r < 4; ++r) {
            int m = q * 4 + r;
            gw[m * 132 + n] = fmaxf(acc[t][r] * sc[r] + bv, 0.f);
        }
    }

    // ---- GEMM2: hd_out = relu(acc + niWd) * dis ----
    load_split_frags(gw + r16 * 132 + q * 8, ahi, alo);
#pragma unroll
    for (int t = 0; t < 8; ++t) acc[t] = {0.f, 0.f, 0.f, 0.f};
    mfma_tiles(ahi, alo, hi_wd, lo_wd, r16, q, acc);

#pragma unroll
    for (int t = 0; t < 8; ++t) {
        int n = t * 16 + r16;
#pragma unroll
        for (int r = 0; r < 4; ++r) {
            long node = base + q * 4 + r;
            float nv = bf2f(niWd[node * 128 + n]);
            hd_out[node * 128 + n] = f2bf(fmaxf(acc[t][r] + nv, 0.f) * sc[r]);
        }
    }
}

// ---- k_final: fc1 + fc2 fused ----
// hf = relu((hd@Wf1_bot)*sdeg + niWf); out = hf @ Wf2 + bf2   ([N,2] f32)
__global__ void __launch_bounds__(256) k_final(
    const ushort_t* __restrict__ in, const ushort_t* __restrict__ WThi,
    const ushort_t* __restrict__ WTlo, const ushort_t* __restrict__ niWf,
    const float* __restrict__ sdeg, const float* __restrict__ Wf2,
    const float* __restrict__ bf2v, float* __restrict__ out) {
    int task = blockIdx.x * 4 + (threadIdx.x >> 6);
    if (task >= NTASK) return;
    int lane = threadIdx.x & 63;
    int q = lane >> 4, r16 = lane & 15;
    long base = (long)task * 16;

    bf16x8 a[4];
    const ushort_t* arow = in + (base + r16) * 128 + q * 8;
#pragma unroll
    for (int kc = 0; kc < 4; ++kc) a[kc] = *(const bf16x8*)(arow + kc * 32);

    f32x4 acc[8];
#pragma unroll
    for (int t = 0; t < 8; ++t) acc[t] = {0.f, 0.f, 0.f, 0.f};
#pragma unroll
    for (int t = 0; t < 8; ++t) {
        const ushort_t* bh = WThi + (t * 16 + r16) * 128 + q * 8;
        const ushort_t* bl = WTlo + (t * 16 + r16) * 128 + q * 8;
#pragma unroll
        for (int kc = 0; kc < 4; ++kc) {
            bf16x8 bhv = *(const bf16x8*)(bh + kc * 32);
            bf16x8 blv = *(const bf16x8*)(bl + kc * 32);
            acc[t] = __builtin_amdgcn_mfma_f32_16x16x32_bf16(a[kc], blv, acc[t], 0, 0, 0);
            acc[t] = __builtin_amdgcn_mfma_f32_16x16x32_bf16(a[kc], bhv, acc[t], 0, 0, 0);
        }
    }

    float sc[4];
#pragma unroll
    for (int r = 0; r < 4; ++r) sc[r] = sdeg[base + q * 4 + r];

    float p0[4] = {0.f, 0.f, 0.f, 0.f}, p1[4] = {0.f, 0.f, 0.f, 0.f};
#pragma unroll
    for (int t = 0; t < 8; ++t) {
        int n = t * 16 + r16;
        float2 w2 = ((const float2*)Wf2)[n];
#pragma unroll
        for (int r = 0; r < 4; ++r) {
            long node = base + q * 4 + r;
            float v = fmaxf(acc[t][r] * sc[r] + bf2f(niWf[node * 128 + n]), 0.f);
            p0[r] += v * w2.x;
            p1[r] += v * w2.y;
        }
    }
#pragma unroll
    for (int step = 1; step < 16; step <<= 1) {
#pragma unroll
        for (int r = 0; r < 4; ++r) {
            p0[r] += __shfl_xor(p0[r], step, 64);
            p1[r] += __shfl_xor(p1[r], step, 64);
        }
    }
    if (r16 == 0) {
        float b0 = bf2v[0], b1v = bf2v[1];
#pragma unroll
        for (int r = 0; r < 4; ++r) {
            long node = base + q * 4 + r;
            float2 o; o.x = p0[r] + b0; o.y = p1[r] + b1v;
            ((float2*)out)[node] = o;
        }
    }
}

extern "C" void kernel_launch(void* const* d_in, const int* in_sizes, int n_in,
                              void* d_out, int out_size, void* d_ws, size_t ws_size,
                              hipStream_t stream) {
    const float* x    = (const float*)d_in[0];
    const int* ei     = (const int*)d_in[1];
    const float* Wp   = (const float*)d_in[2];
    const float* bp   = (const float*)d_in[3];
    const float* W1   = (const float*)d_in[4];
    const float* b1   = (const float*)d_in[5];
    const float* W2   = (const float*)d_in[6];
    const float* b2   = (const float*)d_in[7];
    const float* Wg   = (const float*)d_in[8];
    const float* bg   = (const float*)d_in[9];
    const float* Wd   = (const float*)d_in[10];
    const float* bd   = (const float*)d_in[11];
    const float* Wf1  = (const float*)d_in[12];
    const float* bf1  = (const float*)d_in[13];
    const float* Wf2  = (const float*)d_in[14];
    const float* bf2v = (const float*)d_in[15];

    // workspace carve (256B aligned)
    char* w = (char*)d_ws;
    auto carve = [&](size_t bytes) {
        void* p = (void*)w;
        w += (bytes + 255) & ~(size_t)255;
        return p;
    };
    float* dis      = (float*)carve((size_t)N_NODES * 4);
    float* sdeg     = (float*)carve((size_t)N_NODES * 4);
    unsigned* cnt   = (unsigned*)carve((size_t)N_NODES * 4);
    unsigned* bsum  = (unsigned*)carve((size_t)NB * 4);
    unsigned* prow  = (unsigned*)carve((size_t)(N_NODES + 1) * 4);
    unsigned* colp  = (unsigned*)carve((size_t)COLPAD * 4);
    ushort_t* hdA   = (ushort_t*)carve((size_t)(N_NODES + 1) * 128 * 2);
    ushort_t* hdB   = (ushort_t*)carve((size_t)(N_NODES + 1) * 128 * 2);
    ushort_t* niB   = (ushort_t*)carve((size_t)N_NODES * 128 * 2);
    ushort_t* niWd  = (ushort_t*)carve((size_t)N_NODES * 128 * 2);
    ushort_t* niWf  = (ushort_t*)carve((size_t)N_NODES * 128 * 2);
    ushort_t* WT    = (ushort_t*)carve((size_t)10 * 16384 * 2);
    ushort_t* hi_wdtop  = WT + 0 * 16384; ushort_t* lo_wdtop  = WT + 1 * 16384;
    ushort_t* hi_wf1top = WT + 2 * 16384; ushort_t* lo_wf1top = WT + 3 * 16384;
    ushort_t* hi_wg     = WT + 4 * 16384; ushort_t* lo_wg     = WT + 5 * 16384;
    ushort_t* hi_wdbot  = WT + 6 * 16384; ushort_t* lo_wdbot  = WT + 7 * 16384;
    ushort_t* hi_wf1bot = WT + 8 * 16384; ushort_t* lo_wf1bot = WT + 9 * 16384;

    const int* srcp = ei;
    const int* dstp = ei + N_EDGES;

    const int GE = (N_EDGES + 255) / 256;    // 6250
    const int GP = (COLPAD + 255) / 256;
    const int GG = (NTASK + 3) / 4;          // 1563

    k_init<<<GP, 256, 0, stream>>>(colp, cnt, hdA, hdB);
    k_deg<<<GE, 256, 0, stream>>>(dstp, cnt);
    k_bsum<<<NB, 256, 0, stream>>>(cnt, bsum, dis, sdeg);
    k_apply<<<NB, 256, 0, stream>>>(cnt, bsum, prow, cnt);
    k_fill<<<GE, 256, 0, stream>>>(srcp, dstp, prow, cnt, colp);
    k_tr<<<5, 256, 0, stream>>>(Wd, Wf1, Wg, WT);
    k_pre1<<<N_NODES / 4, 128, 0, stream>>>(x, Wp, bp, W1, b1, W2, b2, dis, niB, hdA);
    k_niw<<<GG, 256, 0, stream>>>(niB, hi_wdtop, lo_wdtop, bd, niWd,
                                  hi_wf1top, lo_wf1top, bf1, niWf);
    ushort_t* hin = hdA;
    ushort_t* hout = hdB;
    for (int l = 0; l < 8; ++l) {
        k_fused<<<GG, 256, 0, stream>>>(prow, colp, hin, hi_wg, lo_wg, bg,
                                        hi_wdbot, lo_wdbot, niWd, dis, hout);
        ushort_t* tmp = hin; hin = hout; hout = tmp;
    }
    k_final<<<GG, 256, 0, stream>>>(hin, hi_wf1bot, lo_wf1bot, niWf, sdeg,
                                    Wf2, bf2v, (float*)d_out);
}